// Round 7
// baseline (760.426 us; speedup 1.0000x reference)
//
#include <hip/hip_runtime.h>
#include <cstdint>
#include <cstddef>

// Problem constants (fixed by the reference)
#define NATOMS 400000
#define NEDGES 1600000
#define NGRAPH 4096
#define F_INN  78
#define HDIM   128
#define FF0D   256
#define FF1D   128

typedef __attribute__((ext_vector_type(8))) short short8;   // 8 bf16 (4 VGPRs)
typedef __attribute__((ext_vector_type(4))) short short4v;  // 4 bf16 (8B store)
typedef __attribute__((ext_vector_type(4))) float f32x4;
typedef __attribute__((ext_vector_type(2))) float f32x2;

// f32 -> bf16 round-to-nearest-even (bit-level)
static __device__ __forceinline__ short f2bf(float f) {
    unsigned u = __builtin_bit_cast(unsigned, f);
    unsigned r = (u + 0x7fffu + ((u >> 16) & 1u)) >> 16;
    return (short)r;
}
static __device__ __forceinline__ float bf2f(unsigned short u) {
    return __builtin_bit_cast(float, ((unsigned)u) << 16);
}

// ---------------- degree + per-edge rank (atomic return value) ----------------
__global__ __launch_bounds__(256) void k_degi(const int* __restrict__ dst,
                                              int* __restrict__ deg,
                                              int* __restrict__ rank, int E) {
    int e = blockIdx.x * 256 + threadIdx.x;
    if (e < E) rank[e] = atomicAdd(&deg[dst[e]], 1);
}

// ---------------- exclusive scan over N ints (3 kernels, in-place) ----------------
// scan1 also emits dinv = rsqrt(deg+1) (deg still intact at entry)
__global__ __launch_bounds__(256) void k_scan1(int* __restrict__ data,
                                               int* __restrict__ blockSums,
                                               float* __restrict__ dinv, int n) {
    __shared__ int ts[256];
    const int base = blockIdx.x * 1024 + threadIdx.x * 4;
    int v[4];
    #pragma unroll
    for (int j = 0; j < 4; ++j) v[j] = (base + j < n) ? data[base + j] : 0;
    #pragma unroll
    for (int j = 0; j < 4; ++j)
        if (base + j < n) dinv[base + j] = rsqrtf((float)v[j] + 1.0f);
    const int tot = v[0] + v[1] + v[2] + v[3];
    ts[threadIdx.x] = tot;
    __syncthreads();
    #pragma unroll
    for (int off = 1; off < 256; off <<= 1) {
        int t = (threadIdx.x >= off) ? ts[threadIdx.x - off] : 0;
        __syncthreads();
        ts[threadIdx.x] += t;
        __syncthreads();
    }
    int run = ts[threadIdx.x] - tot;
    #pragma unroll
    for (int j = 0; j < 4; ++j) {
        if (base + j < n) data[base + j] = run;
        run += v[j];
    }
    if (threadIdx.x == 255) blockSums[blockIdx.x] = ts[255];
}

__global__ __launch_bounds__(512) void k_scan2(int* __restrict__ blockSums, int nb) {
    __shared__ int ts[512];
    int v = (threadIdx.x < nb) ? blockSums[threadIdx.x] : 0;
    ts[threadIdx.x] = v;
    __syncthreads();
    #pragma unroll
    for (int off = 1; off < 512; off <<= 1) {
        int t = (threadIdx.x >= off) ? ts[threadIdx.x - off] : 0;
        __syncthreads();
        ts[threadIdx.x] += t;
        __syncthreads();
    }
    if (threadIdx.x < nb) blockSums[threadIdx.x] = ts[threadIdx.x] - v;
}

__global__ __launch_bounds__(256) void k_scan3(int* __restrict__ data,
                                               const int* __restrict__ blockSums,
                                               int n, int total) {
    const int off = blockSums[blockIdx.x];
    const int base = blockIdx.x * 1024 + threadIdx.x * 4;
    #pragma unroll
    for (int j = 0; j < 4; ++j)
        if (base + j < n) data[base + j] += off;
    if (blockIdx.x == 0 && threadIdx.x == 0) data[n] = total;
}

// ---------------- CSR fill: atomic-free (pos = row_start[d] + rank[e]) ----------
__global__ __launch_bounds__(256) void k_fill(const int* __restrict__ src,
                                              const int* __restrict__ dst,
                                              const int* __restrict__ row_start,
                                              const int* __restrict__ rank,
                                              int2* __restrict__ csr_ev,
                                              const float* __restrict__ dinv, int E) {
    int e = blockIdx.x * 256 + threadIdx.x;
    if (e >= E) return;
    int d = dst[e];
    int s = src[e];
    int pos = row_start[d] + rank[e];
    float norm = dinv[s] * dinv[d];
    csr_ev[pos] = make_int2(s, __builtin_bit_cast(int, norm));
}

// ---------------- weight pack: W [KSRC][128] f32 -> MFMA fragment order bf16 ----
// Used as the A-operand now (A[feat][k]: lane&15 = feat, k = (lane>>4)*8 + j) —
// identical gather pattern to the old B-pack (fragment layouts are transposes).
template<int KC, int KSRC>
__global__ __launch_bounds__(64) void k_packw(const float* __restrict__ W,
                                              short* __restrict__ wf) {
    int t = blockIdx.x * 64 + threadIdx.x;      // t = f*64 + lane
    int f = t >> 6, lane = t & 63;
    int ct = f / KC, kc = f % KC;
    int n  = ct * 16 + (lane & 15);
    int k0 = kc * 32 + (lane >> 4) * 8;
    short8 o;
    #pragma unroll
    for (int j = 0; j < 8; ++j) {
        int k = k0 + j;
        float v = (k < KSRC) ? W[(size_t)k * 128 + n] : 0.f;
        o[j] = f2bf(v);
    }
    *(short8*)(wf + (size_t)t * 8) = o;
}

// ---------------- MFMA GEMM: out[M,128] = in[M,KSRC] @ W  (bf16 out) ----------------
// Operand-swapped: A = W fragments (VGPR-resident), B = node-row fragments.
// D[feat][node]: col=lane&15=node, row=(lane>>4)*4+r = feat-within-tile -> each lane
// stores 4 consecutive feats of one node as one aligned 8B short4.
template<int KC, bool F32IN, int KSRC>
__global__ __launch_bounds__(256) void k_gemm_mfma(
    const void* __restrict__ inv, const short* __restrict__ wfrag,
    short* __restrict__ outp, int M)
{
    constexpr int RT = 5;
    const int wid  = threadIdx.x >> 6;
    const int lane = threadIdx.x & 63;
    const int m = lane & 15, q = lane >> 4;
    const int rowbase = blockIdx.x * (4 * RT * 16) + wid * (RT * 16);

    short8 bfr[8 * KC];
    #pragma unroll
    for (int f = 0; f < 8 * KC; ++f)
        bfr[f] = *(const short8*)(wfrag + ((size_t)(f * 64 + lane)) * 8);

    for (int rt = 0; rt < RT; ++rt) {
        const int rowa = rowbase + rt * 16 + m;
        short8 afr[KC];
        if constexpr (F32IN) {
            const float* xr = (const float*)inv + (size_t)rowa * KSRC;
            #pragma unroll
            for (int kc = 0; kc < KC; ++kc) {
                const int k0 = kc * 32 + q * 8;
                float v[8];
                #pragma unroll
                for (int j = 0; j < 8; ++j) v[j] = 0.f;
                if (k0 < KSRC) {
                    #pragma unroll
                    for (int p = 0; p < 4; ++p) {
                        int k = k0 + 2 * p;
                        if (k < KSRC) {       // KSRC even: pairs never straddle
                            f32x2 t = __builtin_nontemporal_load((const f32x2*)(xr + k));
                            v[2 * p] = t.x; v[2 * p + 1] = t.y;
                        }
                    }
                }
                short8 a;
                #pragma unroll
                for (int j = 0; j < 8; ++j) a[j] = f2bf(v[j]);
                afr[kc] = a;
            }
        } else {
            const short* xr = (const short*)inv + (size_t)rowa * KSRC;
            #pragma unroll
            for (int kc = 0; kc < KC; ++kc)
                afr[kc] = __builtin_nontemporal_load((const short8*)(xr + kc * 32 + q * 8));
        }

        f32x4 acc[8];
        #pragma unroll
        for (int ct = 0; ct < 8; ++ct) acc[ct] = (f32x4){0.f, 0.f, 0.f, 0.f};
        #pragma unroll
        for (int kc = 0; kc < KC; ++kc)
            #pragma unroll
            for (int ct = 0; ct < 8; ++ct)
                acc[ct] = __builtin_amdgcn_mfma_f32_16x16x32_bf16(
                    bfr[ct * KC + kc], afr[kc], acc[ct], 0, 0, 0);

        // D[feat][node]: this lane owns node (rowbase+rt*16+m), feats ct*16+q*4+r
        const size_t nodeoff = (size_t)(rowbase + rt * 16 + m) * 128;
        #pragma unroll
        for (int ct = 0; ct < 8; ++ct) {
            short4v o;
            o.x = f2bf(acc[ct][0]);
            o.y = f2bf(acc[ct][1]);
            o.z = f2bf(acc[ct][2]);
            o.w = f2bf(acc[ct][3]);
            *(short4v*)(outp + nodeoff + ct * 16 + q * 4) = o;
        }
    }
}

// ---------------- gather aggregation: 16 lanes/node, 4-edge unroll, nt store ------
// out[n] = relu(bias + hw[n]*dinv[n]^2 + sum_s hw[s]*norm(s,n))
__global__ __launch_bounds__(256) void k_gather_bf(
    const unsigned short* __restrict__ hw, unsigned short* __restrict__ agg,
    const int* __restrict__ row_start, const int2* __restrict__ csr_ev,
    const float* __restrict__ dinv, const float* __restrict__ bias, int Nn)
{
    const int n  = blockIdx.x * 16 + (threadIdx.x >> 4);
    const int c8 = (threadIdx.x & 15) * 8;
    const float dv = dinv[n];
    const float d2 = dv * dv;

    float acc[8];
    {
        const short8 sv = *(const short8*)(hw + (size_t)n * HDIM + c8);
        #pragma unroll
        for (int j = 0; j < 8; ++j)
            acc[j] = fmaf(bf2f((unsigned short)sv[j]), d2, bias[c8 + j]);
    }

    const int s0 = row_start[n], s1 = row_start[n + 1];
    int i = s0;
    for (; i + 3 < s1; i += 4) {
        const int2 e0 = csr_ev[i];
        const int2 e1 = csr_ev[i + 1];
        const int2 e2 = csr_ev[i + 2];
        const int2 e3 = csr_ev[i + 3];
        const short8 r0 = *(const short8*)(hw + (size_t)e0.x * HDIM + c8);
        const short8 r1 = *(const short8*)(hw + (size_t)e1.x * HDIM + c8);
        const short8 r2 = *(const short8*)(hw + (size_t)e2.x * HDIM + c8);
        const short8 r3 = *(const short8*)(hw + (size_t)e3.x * HDIM + c8);
        const float w0 = __builtin_bit_cast(float, e0.y);
        const float w1 = __builtin_bit_cast(float, e1.y);
        const float w2 = __builtin_bit_cast(float, e2.y);
        const float w3 = __builtin_bit_cast(float, e3.y);
        #pragma unroll
        for (int j = 0; j < 8; ++j) acc[j] = fmaf(bf2f((unsigned short)r0[j]), w0, acc[j]);
        #pragma unroll
        for (int j = 0; j < 8; ++j) acc[j] = fmaf(bf2f((unsigned short)r1[j]), w1, acc[j]);
        #pragma unroll
        for (int j = 0; j < 8; ++j) acc[j] = fmaf(bf2f((unsigned short)r2[j]), w2, acc[j]);
        #pragma unroll
        for (int j = 0; j < 8; ++j) acc[j] = fmaf(bf2f((unsigned short)r3[j]), w3, acc[j]);
    }
    for (; i < s1; ++i) {
        const int2 e0 = csr_ev[i];
        const short8 r0 = *(const short8*)(hw + (size_t)e0.x * HDIM + c8);
        const float w0 = __builtin_bit_cast(float, e0.y);
        #pragma unroll
        for (int j = 0; j < 8; ++j) acc[j] = fmaf(bf2f((unsigned short)r0[j]), w0, acc[j]);
    }

    short8 o;
    #pragma unroll
    for (int j = 0; j < 8; ++j) o[j] = f2bf(fmaxf(acc[j], 0.f));
    __builtin_nontemporal_store(o, (short8*)(agg + (size_t)n * HDIM + c8));
}

// ---------------- global max pool (rows already bias+relu'd), 256 thr/graph ------
__global__ __launch_bounds__(256) void k_pool(
    const unsigned short* __restrict__ agg,
    const int* __restrict__ batch, float* __restrict__ out, int Nn)
{
    __shared__ int se[2];
    __shared__ float red[256];
    int g = blockIdx.x;
    if (threadIdx.x < 2) {
        int target = g + (int)threadIdx.x;
        int lo = 0, hi = Nn;
        while (lo < hi) {
            int mid = (lo + hi) >> 1;
            if (batch[mid] < target) lo = mid + 1; else hi = mid;
        }
        se[threadIdx.x] = lo;
    }
    __syncthreads();
    const int start = se[0], end = se[1];
    const int c = threadIdx.x & 127;
    const int half = threadIdx.x >> 7;
    float m = 0.f;   // post-relu values >= 0; segments non-empty
    for (int i = start + half; i < end; i += 2)
        m = fmaxf(m, bf2f(__builtin_nontemporal_load(agg + (size_t)i * HDIM + c)));
    red[threadIdx.x] = m;
    __syncthreads();
    if (half == 0)
        out[(size_t)g * HDIM + c] = fmaxf(red[threadIdx.x], red[threadIdx.x + 128]);
}

// ---------------- f32 register-blocked GEMM (FF head only, tiny) ----------------
template<int K, int NC, bool OUT_RELU_BIAS>
__global__ __launch_bounds__(256) void k_gemm(
    const float* __restrict__ in, const float* __restrict__ W,
    const float* __restrict__ out_bias, float* __restrict__ out0, int M)
{
    constexpr int BK = 32;
    constexpr int TC = NC / 8;
    constexpr int TR = 256 / TC;
    constexpr int ROWS = TR * 8;
    constexpr int XST = ROWS + 4;

    __shared__ float xs[BK][XST];
    __shared__ float ws[BK][NC];

    const int tid = threadIdx.x;
    const int tc  = tid % TC;
    const int tr  = tid / TC;
    const int row0 = blockIdx.x * ROWS;

    float acc[8][8];
    #pragma unroll
    for (int i = 0; i < 8; ++i)
        #pragma unroll
        for (int j = 0; j < 8; ++j) acc[i][j] = 0.f;

    for (int k0 = 0; k0 < K; k0 += BK) {
        {
            constexpr int TASKS = BK * NC / 4;
            #pragma unroll
            for (int it = 0; it < TASKS / 256; ++it) {
                int t  = it * 256 + tid;
                int wk = t / (NC / 4);
                int wc = (t % (NC / 4)) * 4;
                *(float4*)(&ws[wk][wc]) = *(const float4*)(W + (size_t)(k0 + wk) * NC + wc);
            }
        }
        {
            constexpr int TASKS = ROWS * BK / 4;
            #pragma unroll
            for (int it = 0; it < TASKS / 256; ++it) {
                int t   = it * 256 + tid;
                int r   = t / (BK / 4);
                int kq  = (t % (BK / 4)) * 4;
                float4 x4 = *(const float4*)(in + (size_t)(row0 + r) * K + k0 + kq);
                xs[kq + 0][r] = x4.x; xs[kq + 1][r] = x4.y;
                xs[kq + 2][r] = x4.z; xs[kq + 3][r] = x4.w;
            }
        }
        __syncthreads();
        #pragma unroll 8
        for (int kk = 0; kk < BK; ++kk) {
            float a[8], b[8];
            #pragma unroll
            for (int i = 0; i < 8; ++i) a[i] = xs[kk][tr * 8 + i];
            #pragma unroll
            for (int j = 0; j < 8; ++j) b[j] = ws[kk][tc * 8 + j];
            #pragma unroll
            for (int i = 0; i < 8; ++i)
                #pragma unroll
                for (int j = 0; j < 8; ++j)
                    acc[i][j] = fmaf(a[i], b[j], acc[i][j]);
        }
        __syncthreads();
    }

    #pragma unroll
    for (int i = 0; i < 8; ++i) {
        const int row = row0 + tr * 8 + i;
        #pragma unroll
        for (int jq = 0; jq < 2; ++jq) {
            const int col = tc * 8 + jq * 4;
            float4 v;
            v.x = acc[i][jq * 4 + 0]; v.y = acc[i][jq * 4 + 1];
            v.z = acc[i][jq * 4 + 2]; v.w = acc[i][jq * 4 + 3];
            if constexpr (OUT_RELU_BIAS) {
                const float4 bb = *(const float4*)(out_bias + col);
                v.x = fmaxf(v.x + bb.x, 0.f); v.y = fmaxf(v.y + bb.y, 0.f);
                v.z = fmaxf(v.z + bb.z, 0.f); v.w = fmaxf(v.w + bb.w, 0.f);
            }
            *(float4*)(out0 + (size_t)row * NC + col) = v;
        }
    }
}

extern "C" void kernel_launch(void* const* d_in, const int* in_sizes, int n_in,
                              void* d_out, int out_size, void* d_ws, size_t ws_size,
                              hipStream_t stream) {
    const float* x    = (const float*)d_in[0];
    const int*   ei   = (const int*)d_in[1];
    const int*   batch= (const int*)d_in[2];
    const float* W0   = (const float*)d_in[3];
    const float* b0   = (const float*)d_in[4];
    const float* W1   = (const float*)d_in[5];
    const float* b1   = (const float*)d_in[6];
    const float* Wf0  = (const float*)d_in[7];
    const float* bf0  = (const float*)d_in[8];
    const float* Wf1  = (const float*)d_in[9];
    const float* bf1  = (const float*)d_in[10];
    float* out = (float*)d_out;

    const int* srcI = ei;
    const int* dstI = ei + NEDGES;

    constexpr int SCAN_NBLK = (NATOMS + 1023) / 1024;   // 391

    // workspace layout — total ~227.2 MB (round-6 proven envelope).
    // rank ALIASES the start of aggB: rank's lifetime (degi -> fill) ends before the
    // first gather writes aggB. All blocks 64B-aligned.
    char* base = (char*)d_ws;
    unsigned short* hwA  = (unsigned short*)(base + 0);              // N*128 bf16 = 102,400,000
    unsigned short* aggB = (unsigned short*)(base + 102400000);      // N*128 bf16 = 102,400,000
    int*   rank      = (int*)(base + 102400000);                     // E ints (alias of aggB)
    float* dinv      = (float*)(base + 204800000);                   // N f32 = 1,600,000
    int*   row_start = (int*)(base + 206400000);                     // N+1 ints
    int2*  csr_ev    = (int2*)(base + 208000064);                    // E int2 = 12,800,000
    int*   blockSums = (int*)(base + 220800064);                     // 512 ints
    float* pool      = (float*)(base + 220802112);                   // G*128 f32 = 2,097,152
    float* ff0       = (float*)(base + 222899264);                   // G*256 f32 = 4,194,304
    short* wf0       = (short*)(base + 227093568);                   // 8*3*64*8 bf16 = 24,576 B
    short* wf1       = (short*)(base + 227118144);                   // 8*4*64*8 bf16 = 32,768 B

    // 1) degree (+rank) -> scan (+dinv) -> atomic-free CSR fill
    hipMemsetAsync(row_start, 0, (size_t)(NATOMS + 1) * sizeof(int), stream);
    k_degi<<<(NEDGES + 255) / 256, 256, 0, stream>>>(dstI, row_start, rank, NEDGES);
    k_scan1<<<SCAN_NBLK, 256, 0, stream>>>(row_start, blockSums, dinv, NATOMS);
    k_scan2<<<1, 512, 0, stream>>>(blockSums, SCAN_NBLK);
    k_scan3<<<SCAN_NBLK, 256, 0, stream>>>(row_start, blockSums, NATOMS, NEDGES);
    k_fill<<<(NEDGES + 255) / 256, 256, 0, stream>>>(srcI, dstI, row_start, rank,
                                                     csr_ev, dinv, NEDGES);

    // 2) pack weights into MFMA fragment order (bf16)
    k_packw<3, F_INN><<<8 * 3, 64, 0, stream>>>(W0, wf0);
    k_packw<4, HDIM><<<8 * 4, 64, 0, stream>>>(W1, wf1);

    // 3) layer 0: hw0 = x@W0 (bf16) ; gather -> relu(agg + b0) bf16
    k_gemm_mfma<3, true, F_INN><<<1250, 256, 0, stream>>>(x, wf0, (short*)hwA, NATOMS);
    k_gather_bf<<<NATOMS / 16, 256, 0, stream>>>(hwA, aggB, row_start, csr_ev,
                                                 dinv, b0, NATOMS);

    // 4) layer 1: hw1 = h@W1 (bf16) ; gather -> relu(agg + b1) bf16
    k_gemm_mfma<4, false, HDIM><<<1250, 256, 0, stream>>>(aggB, wf1, (short*)hwA, NATOMS);
    k_gather_bf<<<NATOMS / 16, 256, 0, stream>>>(hwA, aggB, row_start, csr_ev,
                                                 dinv, b1, NATOMS);

    // 5) pool: segment max -> pool f32 [G,128]
    k_pool<<<NGRAPH, 256, 0, stream>>>(aggB, batch, pool, NATOMS);

    // 6) FF head (f32, tiny)
    k_gemm<HDIM, FF0D, true><<<NGRAPH / 64, 256, 0, stream>>>(pool, Wf0, bf0, ff0, NGRAPH);
    k_gemm<FF0D, FF1D, true><<<NGRAPH / 128, 256, 0, stream>>>(ff0, Wf1, bf1, out, NGRAPH);
}

// Round 8
// 747.365 us; speedup vs baseline: 1.0175x; 1.0175x over previous
//
#include <hip/hip_runtime.h>
#include <cstdint>
#include <cstddef>

// Problem constants (fixed by the reference)
#define NATOMS 400000
#define NEDGES 1600000
#define NGRAPH 4096
#define F_INN  78
#define HDIM   128
#define FF0D   256
#define FF1D   128

typedef __attribute__((ext_vector_type(8))) short short8;   // 8 bf16 (4 VGPRs)
typedef __attribute__((ext_vector_type(4))) short short4v;  // 4 bf16 (8B store)
typedef __attribute__((ext_vector_type(4))) float f32x4;
typedef __attribute__((ext_vector_type(2))) float f32x2;

// f32 -> bf16 round-to-nearest-even (bit-level)
static __device__ __forceinline__ short f2bf(float f) {
    unsigned u = __builtin_bit_cast(unsigned, f);
    unsigned r = (u + 0x7fffu + ((u >> 16) & 1u)) >> 16;
    return (short)r;
}
static __device__ __forceinline__ float bf2f(unsigned short u) {
    return __builtin_bit_cast(float, ((unsigned)u) << 16);
}

// ---------------- degree + per-edge rank (atomic return value) ----------------
__global__ __launch_bounds__(256) void k_degi(const int* __restrict__ dst,
                                              int* __restrict__ deg,
                                              int* __restrict__ rank, int E) {
    int e = blockIdx.x * 256 + threadIdx.x;
    if (e < E) rank[e] = atomicAdd(&deg[dst[e]], 1);
}

// ---------------- exclusive scan over N ints (3 kernels, in-place) ----------------
// scan1 also emits dinv = rsqrt(deg+1) (deg still intact at entry)
__global__ __launch_bounds__(256) void k_scan1(int* __restrict__ data,
                                               int* __restrict__ blockSums,
                                               float* __restrict__ dinv, int n) {
    __shared__ int ts[256];
    const int base = blockIdx.x * 1024 + threadIdx.x * 4;
    int v[4];
    #pragma unroll
    for (int j = 0; j < 4; ++j) v[j] = (base + j < n) ? data[base + j] : 0;
    #pragma unroll
    for (int j = 0; j < 4; ++j)
        if (base + j < n) dinv[base + j] = rsqrtf((float)v[j] + 1.0f);
    const int tot = v[0] + v[1] + v[2] + v[3];
    ts[threadIdx.x] = tot;
    __syncthreads();
    #pragma unroll
    for (int off = 1; off < 256; off <<= 1) {
        int t = (threadIdx.x >= off) ? ts[threadIdx.x - off] : 0;
        __syncthreads();
        ts[threadIdx.x] += t;
        __syncthreads();
    }
    int run = ts[threadIdx.x] - tot;
    #pragma unroll
    for (int j = 0; j < 4; ++j) {
        if (base + j < n) data[base + j] = run;
        run += v[j];
    }
    if (threadIdx.x == 255) blockSums[blockIdx.x] = ts[255];
}

__global__ __launch_bounds__(512) void k_scan2(int* __restrict__ blockSums, int nb) {
    __shared__ int ts[512];
    int v = (threadIdx.x < nb) ? blockSums[threadIdx.x] : 0;
    ts[threadIdx.x] = v;
    __syncthreads();
    #pragma unroll
    for (int off = 1; off < 512; off <<= 1) {
        int t = (threadIdx.x >= off) ? ts[threadIdx.x - off] : 0;
        __syncthreads();
        ts[threadIdx.x] += t;
        __syncthreads();
    }
    if (threadIdx.x < nb) blockSums[threadIdx.x] = ts[threadIdx.x] - v;
}

__global__ __launch_bounds__(256) void k_scan3(int* __restrict__ data,
                                               const int* __restrict__ blockSums,
                                               int n, int total) {
    const int off = blockSums[blockIdx.x];
    const int base = blockIdx.x * 1024 + threadIdx.x * 4;
    #pragma unroll
    for (int j = 0; j < 4; ++j)
        if (base + j < n) data[base + j] += off;
    if (blockIdx.x == 0 && threadIdx.x == 0) data[n] = total;
}

// ---------------- CSR fill: atomic-free (pos = row_start[d] + rank[e]) ----------
__global__ __launch_bounds__(256) void k_fill(const int* __restrict__ src,
                                              const int* __restrict__ dst,
                                              const int* __restrict__ row_start,
                                              const int* __restrict__ rank,
                                              int2* __restrict__ csr_ev,
                                              const float* __restrict__ dinv, int E) {
    int e = blockIdx.x * 256 + threadIdx.x;
    if (e >= E) return;
    int d = dst[e];
    int s = src[e];
    int pos = row_start[d] + rank[e];
    float norm = dinv[s] * dinv[d];
    csr_ev[pos] = make_int2(s, __builtin_bit_cast(int, norm));
}

// ---------------- weight pack: W [KSRC][128] f32 -> MFMA A-fragment order bf16 ----
// A[feat][k]: lane&15 = feat-within-tile ct, k = kc*32 + (lane>>4)*8 + j
template<int KC, int KSRC>
__global__ __launch_bounds__(64) void k_packw(const float* __restrict__ W,
                                              short* __restrict__ wf) {
    int t = blockIdx.x * 64 + threadIdx.x;      // t = f*64 + lane
    int f = t >> 6, lane = t & 63;
    int ct = f / KC, kc = f % KC;
    int n  = ct * 16 + (lane & 15);
    int k0 = kc * 32 + (lane >> 4) * 8;
    short8 o;
    #pragma unroll
    for (int j = 0; j < 8; ++j) {
        int k = k0 + j;
        float v = (k < KSRC) ? W[(size_t)k * 128 + n] : 0.f;
        o[j] = f2bf(v);
    }
    *(short8*)(wf + (size_t)t * 8) = o;
}

// ---------------- MFMA GEMM: out[M,128] = in[M,KSRC] @ W  (bf16 out) ----------------
// Weight fragments staged in LDS once per block (keeps VGPRs low -> occupancy high).
// A = W fragment (from LDS), B = node-row fragment (prefetched 1 tile ahead).
// D[feat][node]: col=lane&15=node, row=(lane>>4)*4+r -> one 8B short4 store per ct.
template<int KC, bool F32IN, int KSRC>
__global__ __launch_bounds__(256) void k_gemm_mfma(
    const void* __restrict__ inv, const short* __restrict__ wfrag,
    short* __restrict__ outp, int M)
{
    constexpr int RT = 2;                       // row-tiles per wave
    constexpr int NFRAG = 8 * KC;               // fragments (ct x kc)
    __shared__ short lds_w[NFRAG * 64 * 8];     // KC=4: 32 KB, KC=3: 24 KB

    const int tid = threadIdx.x;
    // ---- stage weight fragments into LDS (linear copy, 16B per thread-iter) ----
    #pragma unroll
    for (int it = 0; it < NFRAG * 64 / 256; ++it) {
        int t = it * 256 + tid;
        *(short8*)(lds_w + (size_t)t * 8) = *(const short8*)(wfrag + (size_t)t * 8);
    }
    __syncthreads();

    const int wid  = tid >> 6;
    const int lane = tid & 63;
    const int m = lane & 15, q = lane >> 4;
    const int rowbase = blockIdx.x * (4 * RT * 16) + wid * (RT * 16);

    // A-fragment (node rows) loader for one 16-row tile
    auto load_afr = [&](int rt, short8* afr) {
        const int rowa = rowbase + rt * 16 + m;
        if constexpr (F32IN) {
            const float* xr = (const float*)inv + (size_t)rowa * KSRC;
            #pragma unroll
            for (int kc = 0; kc < KC; ++kc) {
                const int k0 = kc * 32 + q * 8;
                float v[8];
                #pragma unroll
                for (int j = 0; j < 8; ++j) v[j] = 0.f;
                if (k0 < KSRC) {
                    #pragma unroll
                    for (int p = 0; p < 4; ++p) {
                        int k = k0 + 2 * p;
                        if (k < KSRC) {       // KSRC even: pairs never straddle
                            f32x2 t = __builtin_nontemporal_load((const f32x2*)(xr + k));
                            v[2 * p] = t.x; v[2 * p + 1] = t.y;
                        }
                    }
                }
                short8 a;
                #pragma unroll
                for (int j = 0; j < 8; ++j) a[j] = f2bf(v[j]);
                afr[kc] = a;
            }
        } else {
            const short* xr = (const short*)inv + (size_t)rowa * KSRC;
            #pragma unroll
            for (int kc = 0; kc < KC; ++kc)
                afr[kc] = __builtin_nontemporal_load((const short8*)(xr + kc * 32 + q * 8));
        }
    };

    short8 afr[KC], afrN[KC];
    load_afr(0, afr);

    #pragma unroll
    for (int rt = 0; rt < RT; ++rt) {
        if (rt + 1 < RT) load_afr(rt + 1, afrN);   // prefetch next tile

        f32x4 acc[8];
        #pragma unroll
        for (int ct = 0; ct < 8; ++ct) acc[ct] = (f32x4){0.f, 0.f, 0.f, 0.f};
        #pragma unroll
        for (int kc = 0; kc < KC; ++kc)
            #pragma unroll
            for (int ct = 0; ct < 8; ++ct) {
                const short8 wv = *(const short8*)(lds_w + ((size_t)((ct * KC + kc) * 64 + lane)) * 8);
                acc[ct] = __builtin_amdgcn_mfma_f32_16x16x32_bf16(wv, afr[kc], acc[ct], 0, 0, 0);
            }

        // D[feat][node]: lane owns node (rowbase+rt*16+m), feats ct*16+q*4 .. +3
        const size_t nodeoff = (size_t)(rowbase + rt * 16 + m) * 128;
        #pragma unroll
        for (int ct = 0; ct < 8; ++ct) {
            short4v o;
            o.x = f2bf(acc[ct][0]);
            o.y = f2bf(acc[ct][1]);
            o.z = f2bf(acc[ct][2]);
            o.w = f2bf(acc[ct][3]);
            *(short4v*)(outp + nodeoff + ct * 16 + q * 4) = o;
        }

        #pragma unroll
        for (int kc = 0; kc < KC; ++kc) afr[kc] = afrN[kc];
    }
}

// ---------------- gather aggregation: 16 lanes/node, 4-edge unroll, nt store ------
// out[n] = relu(bias + hw[n]*dinv[n]^2 + sum_s hw[s]*norm(s,n))
__global__ __launch_bounds__(256) void k_gather_bf(
    const unsigned short* __restrict__ hw, unsigned short* __restrict__ agg,
    const int* __restrict__ row_start, const int2* __restrict__ csr_ev,
    const float* __restrict__ dinv, const float* __restrict__ bias, int Nn)
{
    const int n  = blockIdx.x * 16 + (threadIdx.x >> 4);
    const int c8 = (threadIdx.x & 15) * 8;
    const float dv = dinv[n];
    const float d2 = dv * dv;

    float acc[8];
    {
        const short8 sv = *(const short8*)(hw + (size_t)n * HDIM + c8);
        #pragma unroll
        for (int j = 0; j < 8; ++j)
            acc[j] = fmaf(bf2f((unsigned short)sv[j]), d2, bias[c8 + j]);
    }

    const int s0 = row_start[n], s1 = row_start[n + 1];
    int i = s0;
    for (; i + 3 < s1; i += 4) {
        const int2 e0 = csr_ev[i];
        const int2 e1 = csr_ev[i + 1];
        const int2 e2 = csr_ev[i + 2];
        const int2 e3 = csr_ev[i + 3];
        const short8 r0 = *(const short8*)(hw + (size_t)e0.x * HDIM + c8);
        const short8 r1 = *(const short8*)(hw + (size_t)e1.x * HDIM + c8);
        const short8 r2 = *(const short8*)(hw + (size_t)e2.x * HDIM + c8);
        const short8 r3 = *(const short8*)(hw + (size_t)e3.x * HDIM + c8);
        const float w0 = __builtin_bit_cast(float, e0.y);
        const float w1 = __builtin_bit_cast(float, e1.y);
        const float w2 = __builtin_bit_cast(float, e2.y);
        const float w3 = __builtin_bit_cast(float, e3.y);
        #pragma unroll
        for (int j = 0; j < 8; ++j) acc[j] = fmaf(bf2f((unsigned short)r0[j]), w0, acc[j]);
        #pragma unroll
        for (int j = 0; j < 8; ++j) acc[j] = fmaf(bf2f((unsigned short)r1[j]), w1, acc[j]);
        #pragma unroll
        for (int j = 0; j < 8; ++j) acc[j] = fmaf(bf2f((unsigned short)r2[j]), w2, acc[j]);
        #pragma unroll
        for (int j = 0; j < 8; ++j) acc[j] = fmaf(bf2f((unsigned short)r3[j]), w3, acc[j]);
    }
    for (; i < s1; ++i) {
        const int2 e0 = csr_ev[i];
        const short8 r0 = *(const short8*)(hw + (size_t)e0.x * HDIM + c8);
        const float w0 = __builtin_bit_cast(float, e0.y);
        #pragma unroll
        for (int j = 0; j < 8; ++j) acc[j] = fmaf(bf2f((unsigned short)r0[j]), w0, acc[j]);
    }

    short8 o;
    #pragma unroll
    for (int j = 0; j < 8; ++j) o[j] = f2bf(fmaxf(acc[j], 0.f));
    __builtin_nontemporal_store(o, (short8*)(agg + (size_t)n * HDIM + c8));
}

// ---------------- global max pool (rows already bias+relu'd), 256 thr/graph ------
__global__ __launch_bounds__(256) void k_pool(
    const unsigned short* __restrict__ agg,
    const int* __restrict__ batch, float* __restrict__ out, int Nn)
{
    __shared__ int se[2];
    __shared__ float red[256];
    int g = blockIdx.x;
    if (threadIdx.x < 2) {
        int target = g + (int)threadIdx.x;
        int lo = 0, hi = Nn;
        while (lo < hi) {
            int mid = (lo + hi) >> 1;
            if (batch[mid] < target) lo = mid + 1; else hi = mid;
        }
        se[threadIdx.x] = lo;
    }
    __syncthreads();
    const int start = se[0], end = se[1];
    const int c = threadIdx.x & 127;
    const int half = threadIdx.x >> 7;
    float m = 0.f;   // post-relu values >= 0; segments non-empty
    for (int i = start + half; i < end; i += 2)
        m = fmaxf(m, bf2f(__builtin_nontemporal_load(agg + (size_t)i * HDIM + c)));
    red[threadIdx.x] = m;
    __syncthreads();
    if (half == 0)
        out[(size_t)g * HDIM + c] = fmaxf(red[threadIdx.x], red[threadIdx.x + 128]);
}

// ---------------- f32 register-blocked GEMM (FF head only, tiny) ----------------
template<int K, int NC, bool OUT_RELU_BIAS>
__global__ __launch_bounds__(256) void k_gemm(
    const float* __restrict__ in, const float* __restrict__ W,
    const float* __restrict__ out_bias, float* __restrict__ out0, int M)
{
    constexpr int BK = 32;
    constexpr int TC = NC / 8;
    constexpr int TR = 256 / TC;
    constexpr int ROWS = TR * 8;
    constexpr int XST = ROWS + 4;

    __shared__ float xs[BK][XST];
    __shared__ float ws[BK][NC];

    const int tid = threadIdx.x;
    const int tc  = tid % TC;
    const int tr  = tid / TC;
    const int row0 = blockIdx.x * ROWS;

    float acc[8][8];
    #pragma unroll
    for (int i = 0; i < 8; ++i)
        #pragma unroll
        for (int j = 0; j < 8; ++j) acc[i][j] = 0.f;

    for (int k0 = 0; k0 < K; k0 += BK) {
        {
            constexpr int TASKS = BK * NC / 4;
            #pragma unroll
            for (int it = 0; it < TASKS / 256; ++it) {
                int t  = it * 256 + tid;
                int wk = t / (NC / 4);
                int wc = (t % (NC / 4)) * 4;
                *(float4*)(&ws[wk][wc]) = *(const float4*)(W + (size_t)(k0 + wk) * NC + wc);
            }
        }
        {
            constexpr int TASKS = ROWS * BK / 4;
            #pragma unroll
            for (int it = 0; it < TASKS / 256; ++it) {
                int t   = it * 256 + tid;
                int r   = t / (BK / 4);
                int kq  = (t % (BK / 4)) * 4;
                float4 x4 = *(const float4*)(in + (size_t)(row0 + r) * K + k0 + kq);
                xs[kq + 0][r] = x4.x; xs[kq + 1][r] = x4.y;
                xs[kq + 2][r] = x4.z; xs[kq + 3][r] = x4.w;
            }
        }
        __syncthreads();
        #pragma unroll 8
        for (int kk = 0; kk < BK; ++kk) {
            float a[8], b[8];
            #pragma unroll
            for (int i = 0; i < 8; ++i) a[i] = xs[kk][tr * 8 + i];
            #pragma unroll
            for (int j = 0; j < 8; ++j) b[j] = ws[kk][tc * 8 + j];
            #pragma unroll
            for (int i = 0; i < 8; ++i)
                #pragma unroll
                for (int j = 0; j < 8; ++j)
                    acc[i][j] = fmaf(a[i], b[j], acc[i][j]);
        }
        __syncthreads();
    }

    #pragma unroll
    for (int i = 0; i < 8; ++i) {
        const int row = row0 + tr * 8 + i;
        #pragma unroll
        for (int jq = 0; jq < 2; ++jq) {
            const int col = tc * 8 + jq * 4;
            float4 v;
            v.x = acc[i][jq * 4 + 0]; v.y = acc[i][jq * 4 + 1];
            v.z = acc[i][jq * 4 + 2]; v.w = acc[i][jq * 4 + 3];
            if constexpr (OUT_RELU_BIAS) {
                const float4 bb = *(const float4*)(out_bias + col);
                v.x = fmaxf(v.x + bb.x, 0.f); v.y = fmaxf(v.y + bb.y, 0.f);
                v.z = fmaxf(v.z + bb.z, 0.f); v.w = fmaxf(v.w + bb.w, 0.f);
            }
            *(float4*)(out0 + (size_t)row * NC + col) = v;
        }
    }
}

extern "C" void kernel_launch(void* const* d_in, const int* in_sizes, int n_in,
                              void* d_out, int out_size, void* d_ws, size_t ws_size,
                              hipStream_t stream) {
    const float* x    = (const float*)d_in[0];
    const int*   ei   = (const int*)d_in[1];
    const int*   batch= (const int*)d_in[2];
    const float* W0   = (const float*)d_in[3];
    const float* b0   = (const float*)d_in[4];
    const float* W1   = (const float*)d_in[5];
    const float* b1   = (const float*)d_in[6];
    const float* Wf0  = (const float*)d_in[7];
    const float* bf0  = (const float*)d_in[8];
    const float* Wf1  = (const float*)d_in[9];
    const float* bf1  = (const float*)d_in[10];
    float* out = (float*)d_out;

    const int* srcI = ei;
    const int* dstI = ei + NEDGES;

    constexpr int SCAN_NBLK = (NATOMS + 1023) / 1024;   // 391

    // workspace layout — total ~227.2 MB (round-6 proven envelope).
    // rank ALIASES the start of aggB: rank's lifetime (degi -> fill) ends before the
    // first gather writes aggB. All blocks 64B-aligned.
    char* base = (char*)d_ws;
    unsigned short* hwA  = (unsigned short*)(base + 0);              // N*128 bf16 = 102,400,000
    unsigned short* aggB = (unsigned short*)(base + 102400000);      // N*128 bf16 = 102,400,000
    int*   rank      = (int*)(base + 102400000);                     // E ints (alias of aggB)
    float* dinv      = (float*)(base + 204800000);                   // N f32 = 1,600,000
    int*   row_start = (int*)(base + 206400000);                     // N+1 ints
    int2*  csr_ev    = (int2*)(base + 208000064);                    // E int2 = 12,800,000
    int*   blockSums = (int*)(base + 220800064);                     // 512 ints
    float* pool      = (float*)(base + 220802112);                   // G*128 f32 = 2,097,152
    float* ff0       = (float*)(base + 222899264);                   // G*256 f32 = 4,194,304
    short* wf0       = (short*)(base + 227093568);                   // 8*3*64*8 bf16 = 24,576 B
    short* wf1       = (short*)(base + 227118144);                   // 8*4*64*8 bf16 = 32,768 B

    // 1) degree (+rank) -> scan (+dinv) -> atomic-free CSR fill
    hipMemsetAsync(row_start, 0, (size_t)(NATOMS + 1) * sizeof(int), stream);
    k_degi<<<(NEDGES + 255) / 256, 256, 0, stream>>>(dstI, row_start, rank, NEDGES);
    k_scan1<<<SCAN_NBLK, 256, 0, stream>>>(row_start, blockSums, dinv, NATOMS);
    k_scan2<<<1, 512, 0, stream>>>(blockSums, SCAN_NBLK);
    k_scan3<<<SCAN_NBLK, 256, 0, stream>>>(row_start, blockSums, NATOMS, NEDGES);
    k_fill<<<(NEDGES + 255) / 256, 256, 0, stream>>>(srcI, dstI, row_start, rank,
                                                     csr_ev, dinv, NEDGES);

    // 2) pack weights into MFMA fragment order (bf16)
    k_packw<3, F_INN><<<8 * 3, 64, 0, stream>>>(W0, wf0);
    k_packw<4, HDIM><<<8 * 4, 64, 0, stream>>>(W1, wf1);

    // 3) layer 0: hw0 = x@W0 (bf16) ; gather -> relu(agg + b0) bf16
    //    grid = N / (4 waves * RT=2 * 16 rows) = 3125
    k_gemm_mfma<3, true, F_INN><<<3125, 256, 0, stream>>>(x, wf0, (short*)hwA, NATOMS);
    k_gather_bf<<<NATOMS / 16, 256, 0, stream>>>(hwA, aggB, row_start, csr_ev,
                                                 dinv, b0, NATOMS);

    // 4) layer 1: hw1 = h@W1 (bf16) ; gather -> relu(agg + b1) bf16
    k_gemm_mfma<4, false, HDIM><<<3125, 256, 0, stream>>>(aggB, wf1, (short*)hwA, NATOMS);
    k_gather_bf<<<NATOMS / 16, 256, 0, stream>>>(hwA, aggB, row_start, csr_ev,
                                                 dinv, b1, NATOMS);

    // 5) pool: segment max -> pool f32 [G,128]
    k_pool<<<NGRAPH, 256, 0, stream>>>(aggB, batch, pool, NATOMS);

    // 6) FF head (f32, tiny)
    k_gemm<HDIM, FF0D, true><<<NGRAPH / 64, 256, 0, stream>>>(pool, Wf0, bf0, ff0, NGRAPH);
    k_gemm<FF0D, FF1D, true><<<NGRAPH / 128, 256, 0, stream>>>(ff0, Wf1, bf1, out, NGRAPH);
}

// Round 9
// 722.379 us; speedup vs baseline: 1.0527x; 1.0346x over previous
//
#include <hip/hip_runtime.h>
#include <cstdint>
#include <cstddef>

// Problem constants (fixed by the reference)
#define NATOMS 400000
#define NEDGES 1600000
#define NGRAPH 4096
#define F_INN  78
#define HDIM   128
#define FF0D   256
#define FF1D   128

typedef __attribute__((ext_vector_type(8))) short short8;   // 8 bf16 (4 VGPRs)
typedef __attribute__((ext_vector_type(4))) short short4v;  // 4 bf16 (8B store)
typedef __attribute__((ext_vector_type(4))) float f32x4;
typedef __attribute__((ext_vector_type(2))) float f32x2;

// f32 -> bf16 round-to-nearest-even (bit-level)
static __device__ __forceinline__ short f2bf(float f) {
    unsigned u = __builtin_bit_cast(unsigned, f);
    unsigned r = (u + 0x7fffu + ((u >> 16) & 1u)) >> 16;
    return (short)r;
}
static __device__ __forceinline__ float bf2f(unsigned short u) {
    return __builtin_bit_cast(float, ((unsigned)u) << 16);
}

// ---------------- degree + per-edge rank (atomic return value) ----------------
__global__ __launch_bounds__(256) void k_degi(const int* __restrict__ dst,
                                              int* __restrict__ deg,
                                              int* __restrict__ rank, int E) {
    int e = blockIdx.x * 256 + threadIdx.x;
    if (e < E) rank[e] = atomicAdd(&deg[dst[e]], 1);
}

// ---------------- exclusive scan over N ints (3 kernels, in-place) ----------------
// scan1 also emits dinv = rsqrt(deg+1) (deg still intact at entry)
__global__ __launch_bounds__(256) void k_scan1(int* __restrict__ data,
                                               int* __restrict__ blockSums,
                                               float* __restrict__ dinv, int n) {
    __shared__ int ts[256];
    const int base = blockIdx.x * 1024 + threadIdx.x * 4;
    int v[4];
    #pragma unroll
    for (int j = 0; j < 4; ++j) v[j] = (base + j < n) ? data[base + j] : 0;
    #pragma unroll
    for (int j = 0; j < 4; ++j)
        if (base + j < n) dinv[base + j] = rsqrtf((float)v[j] + 1.0f);
    const int tot = v[0] + v[1] + v[2] + v[3];
    ts[threadIdx.x] = tot;
    __syncthreads();
    #pragma unroll
    for (int off = 1; off < 256; off <<= 1) {
        int t = (threadIdx.x >= off) ? ts[threadIdx.x - off] : 0;
        __syncthreads();
        ts[threadIdx.x] += t;
        __syncthreads();
    }
    int run = ts[threadIdx.x] - tot;
    #pragma unroll
    for (int j = 0; j < 4; ++j) {
        if (base + j < n) data[base + j] = run;
        run += v[j];
    }
    if (threadIdx.x == 255) blockSums[blockIdx.x] = ts[255];
}

__global__ __launch_bounds__(512) void k_scan2(int* __restrict__ blockSums, int nb) {
    __shared__ int ts[512];
    int v = (threadIdx.x < nb) ? blockSums[threadIdx.x] : 0;
    ts[threadIdx.x] = v;
    __syncthreads();
    #pragma unroll
    for (int off = 1; off < 512; off <<= 1) {
        int t = (threadIdx.x >= off) ? ts[threadIdx.x - off] : 0;
        __syncthreads();
        ts[threadIdx.x] += t;
        __syncthreads();
    }
    if (threadIdx.x < nb) blockSums[threadIdx.x] = ts[threadIdx.x] - v;
}

__global__ __launch_bounds__(256) void k_scan3(int* __restrict__ data,
                                               const int* __restrict__ blockSums,
                                               int n, int total) {
    const int off = blockSums[blockIdx.x];
    const int base = blockIdx.x * 1024 + threadIdx.x * 4;
    #pragma unroll
    for (int j = 0; j < 4; ++j)
        if (base + j < n) data[base + j] += off;
    if (blockIdx.x == 0 && threadIdx.x == 0) data[n] = total;
}

// ---------------- CSR fill: atomic-free (pos = row_start[d] + rank[e]) ----------
__global__ __launch_bounds__(256) void k_fill(const int* __restrict__ src,
                                              const int* __restrict__ dst,
                                              const int* __restrict__ row_start,
                                              const int* __restrict__ rank,
                                              int2* __restrict__ csr_ev,
                                              const float* __restrict__ dinv, int E) {
    int e = blockIdx.x * 256 + threadIdx.x;
    if (e >= E) return;
    int d = dst[e];
    int s = src[e];
    int pos = row_start[d] + rank[e];
    float norm = dinv[s] * dinv[d];
    csr_ev[pos] = make_int2(s, __builtin_bit_cast(int, norm));
}

// ---------------- weight pack: W [KSRC][128] f32 -> MFMA A-fragment order bf16 ----
// A[feat][k]: lane&15 = feat-within-tile ct, k = kc*32 + (lane>>4)*8 + j
template<int KC, int KSRC>
__global__ __launch_bounds__(64) void k_packw(const float* __restrict__ W,
                                              short* __restrict__ wf) {
    int t = blockIdx.x * 64 + threadIdx.x;      // t = f*64 + lane
    int f = t >> 6, lane = t & 63;
    int ct = f / KC, kc = f % KC;
    int n  = ct * 16 + (lane & 15);
    int k0 = kc * 32 + (lane >> 4) * 8;
    short8 o;
    #pragma unroll
    for (int j = 0; j < 8; ++j) {
        int k = k0 + j;
        float v = (k < KSRC) ? W[(size_t)k * 128 + n] : 0.f;
        o[j] = f2bf(v);
    }
    *(short8*)(wf + (size_t)t * 8) = o;
}

// ---------------- persistent MFMA GEMM: out[M,128] = in[M,KSRC] @ W (bf16 out) ----
// 1024 blocks, fully resident; weights staged to LDS ONCE per block; each wave
// grid-strides over ~6-7 row-tiles of 16 with 1-deep A-fragment prefetch so
// every wave keeps loads in flight for the whole kernel (latency hiding).
// A = W fragment (LDS), B = node-row fragment. D[feat][node]: lane stores 4
// consecutive feats of one node per ct as one aligned 8B short4.
template<int KC, bool F32IN, int KSRC>
__global__ __launch_bounds__(256) void k_gemm_mfma(
    const void* __restrict__ inv, const short* __restrict__ wfrag,
    short* __restrict__ outp, int M)
{
    constexpr int NFRAG = 8 * KC;               // fragments (ct x kc)
    __shared__ short lds_w[NFRAG * 64 * 8];     // KC=4: 32 KB, KC=3: 24 KB

    const int tid = threadIdx.x;
    // ---- stage weight fragments into LDS once ----
    #pragma unroll
    for (int it = 0; it < NFRAG * 64 / 256; ++it) {
        int t = it * 256 + tid;
        *(short8*)(lds_w + (size_t)t * 8) = *(const short8*)(wfrag + (size_t)t * 8);
    }
    __syncthreads();

    const int lane = tid & 63;
    const int m = lane & 15, q = lane >> 4;
    const int gw = blockIdx.x * 4 + (tid >> 6);     // global wave id
    const int NW = gridDim.x * 4;                   // total waves
    const int NTILE = M / 16;

    // A-fragment (node rows) loader for one 16-row tile
    auto load_afr = [&](int tile, short8* afr) {
        const int rowa = tile * 16 + m;
        if constexpr (F32IN) {
            const float* xr = (const float*)inv + (size_t)rowa * KSRC;
            #pragma unroll
            for (int kc = 0; kc < KC; ++kc) {
                const int k0 = kc * 32 + q * 8;
                float v[8];
                #pragma unroll
                for (int j = 0; j < 8; ++j) v[j] = 0.f;
                if (k0 < KSRC) {
                    #pragma unroll
                    for (int p = 0; p < 4; ++p) {
                        int k = k0 + 2 * p;
                        if (k < KSRC) {       // KSRC even: pairs never straddle
                            f32x2 t = *(const f32x2*)(xr + k);
                            v[2 * p] = t.x; v[2 * p + 1] = t.y;
                        }
                    }
                }
                short8 a;
                #pragma unroll
                for (int j = 0; j < 8; ++j) a[j] = f2bf(v[j]);
                afr[kc] = a;
            }
        } else {
            const short* xr = (const short*)inv + (size_t)rowa * KSRC;
            #pragma unroll
            for (int kc = 0; kc < KC; ++kc)
                afr[kc] = *(const short8*)(xr + kc * 32 + q * 8);
        }
    };

    short8 afr[KC], afrN[KC];
    load_afr(gw, afr);    // gw < NTILE always (4096 < 25000)

    for (int t = gw; t < NTILE; t += NW) {
        const int tn = t + NW;
        if (tn < NTILE) load_afr(tn, afrN);     // prefetch next tile

        f32x4 acc[8];
        #pragma unroll
        for (int ct = 0; ct < 8; ++ct) acc[ct] = (f32x4){0.f, 0.f, 0.f, 0.f};
        #pragma unroll
        for (int kc = 0; kc < KC; ++kc)
            #pragma unroll
            for (int ct = 0; ct < 8; ++ct) {
                const short8 wv = *(const short8*)(lds_w + ((size_t)((ct * KC + kc) * 64 + lane)) * 8);
                acc[ct] = __builtin_amdgcn_mfma_f32_16x16x32_bf16(wv, afr[kc], acc[ct], 0, 0, 0);
            }

        // D[feat][node]: lane owns node (t*16+m), feats ct*16+q*4 .. +3
        const size_t nodeoff = (size_t)(t * 16 + m) * 128;
        #pragma unroll
        for (int ct = 0; ct < 8; ++ct) {
            short4v o;
            o.x = f2bf(acc[ct][0]);
            o.y = f2bf(acc[ct][1]);
            o.z = f2bf(acc[ct][2]);
            o.w = f2bf(acc[ct][3]);
            *(short4v*)(outp + nodeoff + ct * 16 + q * 4) = o;
        }

        #pragma unroll
        for (int kc = 0; kc < KC; ++kc) afr[kc] = afrN[kc];
    }
}

// ---------------- gather aggregation: 16 lanes/node, 4-edge unroll, nt store ------
// out[n] = relu(bias + hw[n]*dinv[n]^2 + sum_s hw[s]*norm(s,n))
__global__ __launch_bounds__(256) void k_gather_bf(
    const unsigned short* __restrict__ hw, unsigned short* __restrict__ agg,
    const int* __restrict__ row_start, const int2* __restrict__ csr_ev,
    const float* __restrict__ dinv, const float* __restrict__ bias, int Nn)
{
    const int n  = blockIdx.x * 16 + (threadIdx.x >> 4);
    const int c8 = (threadIdx.x & 15) * 8;
    const float dv = dinv[n];
    const float d2 = dv * dv;

    float acc[8];
    {
        const short8 sv = *(const short8*)(hw + (size_t)n * HDIM + c8);
        #pragma unroll
        for (int j = 0; j < 8; ++j)
            acc[j] = fmaf(bf2f((unsigned short)sv[j]), d2, bias[c8 + j]);
    }

    const int s0 = row_start[n], s1 = row_start[n + 1];
    int i = s0;
    for (; i + 3 < s1; i += 4) {
        const int2 e0 = csr_ev[i];
        const int2 e1 = csr_ev[i + 1];
        const int2 e2 = csr_ev[i + 2];
        const int2 e3 = csr_ev[i + 3];
        const short8 r0 = *(const short8*)(hw + (size_t)e0.x * HDIM + c8);
        const short8 r1 = *(const short8*)(hw + (size_t)e1.x * HDIM + c8);
        const short8 r2 = *(const short8*)(hw + (size_t)e2.x * HDIM + c8);
        const short8 r3 = *(const short8*)(hw + (size_t)e3.x * HDIM + c8);
        const float w0 = __builtin_bit_cast(float, e0.y);
        const float w1 = __builtin_bit_cast(float, e1.y);
        const float w2 = __builtin_bit_cast(float, e2.y);
        const float w3 = __builtin_bit_cast(float, e3.y);
        #pragma unroll
        for (int j = 0; j < 8; ++j) acc[j] = fmaf(bf2f((unsigned short)r0[j]), w0, acc[j]);
        #pragma unroll
        for (int j = 0; j < 8; ++j) acc[j] = fmaf(bf2f((unsigned short)r1[j]), w1, acc[j]);
        #pragma unroll
        for (int j = 0; j < 8; ++j) acc[j] = fmaf(bf2f((unsigned short)r2[j]), w2, acc[j]);
        #pragma unroll
        for (int j = 0; j < 8; ++j) acc[j] = fmaf(bf2f((unsigned short)r3[j]), w3, acc[j]);
    }
    for (; i < s1; ++i) {
        const int2 e0 = csr_ev[i];
        const short8 r0 = *(const short8*)(hw + (size_t)e0.x * HDIM + c8);
        const float w0 = __builtin_bit_cast(float, e0.y);
        #pragma unroll
        for (int j = 0; j < 8; ++j) acc[j] = fmaf(bf2f((unsigned short)r0[j]), w0, acc[j]);
    }

    short8 o;
    #pragma unroll
    for (int j = 0; j < 8; ++j) o[j] = f2bf(fmaxf(acc[j], 0.f));
    __builtin_nontemporal_store(o, (short8*)(agg + (size_t)n * HDIM + c8));
}

// ---------------- global max pool (rows already bias+relu'd), 256 thr/graph ------
__global__ __launch_bounds__(256) void k_pool(
    const unsigned short* __restrict__ agg,
    const int* __restrict__ batch, float* __restrict__ out, int Nn)
{
    __shared__ int se[2];
    __shared__ float red[256];
    int g = blockIdx.x;
    if (threadIdx.x < 2) {
        int target = g + (int)threadIdx.x;
        int lo = 0, hi = Nn;
        while (lo < hi) {
            int mid = (lo + hi) >> 1;
            if (batch[mid] < target) lo = mid + 1; else hi = mid;
        }
        se[threadIdx.x] = lo;
    }
    __syncthreads();
    const int start = se[0], end = se[1];
    const int c = threadIdx.x & 127;
    const int half = threadIdx.x >> 7;
    float m = 0.f;   // post-relu values >= 0; segments non-empty
    for (int i = start + half; i < end; i += 2)
        m = fmaxf(m, bf2f(__builtin_nontemporal_load(agg + (size_t)i * HDIM + c)));
    red[threadIdx.x] = m;
    __syncthreads();
    if (half == 0)
        out[(size_t)g * HDIM + c] = fmaxf(red[threadIdx.x], red[threadIdx.x + 128]);
}

// ---------------- f32 register-blocked GEMM (FF head only, tiny) ----------------
template<int K, int NC, bool OUT_RELU_BIAS>
__global__ __launch_bounds__(256) void k_gemm(
    const float* __restrict__ in, const float* __restrict__ W,
    const float* __restrict__ out_bias, float* __restrict__ out0, int M)
{
    constexpr int BK = 32;
    constexpr int TC = NC / 8;
    constexpr int TR = 256 / TC;
    constexpr int ROWS = TR * 8;
    constexpr int XST = ROWS + 4;

    __shared__ float xs[BK][XST];
    __shared__ float ws[BK][NC];

    const int tid = threadIdx.x;
    const int tc  = tid % TC;
    const int tr  = tid / TC;
    const int row0 = blockIdx.x * ROWS;

    float acc[8][8];
    #pragma unroll
    for (int i = 0; i < 8; ++i)
        #pragma unroll
        for (int j = 0; j < 8; ++j) acc[i][j] = 0.f;

    for (int k0 = 0; k0 < K; k0 += BK) {
        {
            constexpr int TASKS = BK * NC / 4;
            #pragma unroll
            for (int it = 0; it < TASKS / 256; ++it) {
                int t  = it * 256 + tid;
                int wk = t / (NC / 4);
                int wc = (t % (NC / 4)) * 4;
                *(float4*)(&ws[wk][wc]) = *(const float4*)(W + (size_t)(k0 + wk) * NC + wc);
            }
        }
        {
            constexpr int TASKS = ROWS * BK / 4;
            #pragma unroll
            for (int it = 0; it < TASKS / 256; ++it) {
                int t   = it * 256 + tid;
                int r   = t / (BK / 4);
                int kq  = (t % (BK / 4)) * 4;
                float4 x4 = *(const float4*)(in + (size_t)(row0 + r) * K + k0 + kq);
                xs[kq + 0][r] = x4.x; xs[kq + 1][r] = x4.y;
                xs[kq + 2][r] = x4.z; xs[kq + 3][r] = x4.w;
            }
        }
        __syncthreads();
        #pragma unroll 8
        for (int kk = 0; kk < BK; ++kk) {
            float a[8], b[8];
            #pragma unroll
            for (int i = 0; i < 8; ++i) a[i] = xs[kk][tr * 8 + i];
            #pragma unroll
            for (int j = 0; j < 8; ++j) b[j] = ws[kk][tc * 8 + j];
            #pragma unroll
            for (int i = 0; i < 8; ++i)
                #pragma unroll
                for (int j = 0; j < 8; ++j)
                    acc[i][j] = fmaf(a[i], b[j], acc[i][j]);
        }
        __syncthreads();
    }

    #pragma unroll
    for (int i = 0; i < 8; ++i) {
        const int row = row0 + tr * 8 + i;
        #pragma unroll
        for (int jq = 0; jq < 2; ++jq) {
            const int col = tc * 8 + jq * 4;
            float4 v;
            v.x = acc[i][jq * 4 + 0]; v.y = acc[i][jq * 4 + 1];
            v.z = acc[i][jq * 4 + 2]; v.w = acc[i][jq * 4 + 3];
            if constexpr (OUT_RELU_BIAS) {
                const float4 bb = *(const float4*)(out_bias + col);
                v.x = fmaxf(v.x + bb.x, 0.f); v.y = fmaxf(v.y + bb.y, 0.f);
                v.z = fmaxf(v.z + bb.z, 0.f); v.w = fmaxf(v.w + bb.w, 0.f);
            }
            *(float4*)(out0 + (size_t)row * NC + col) = v;
        }
    }
}

extern "C" void kernel_launch(void* const* d_in, const int* in_sizes, int n_in,
                              void* d_out, int out_size, void* d_ws, size_t ws_size,
                              hipStream_t stream) {
    const float* x    = (const float*)d_in[0];
    const int*   ei   = (const int*)d_in[1];
    const int*   batch= (const int*)d_in[2];
    const float* W0   = (const float*)d_in[3];
    const float* b0   = (const float*)d_in[4];
    const float* W1   = (const float*)d_in[5];
    const float* b1   = (const float*)d_in[6];
    const float* Wf0  = (const float*)d_in[7];
    const float* bf0  = (const float*)d_in[8];
    const float* Wf1  = (const float*)d_in[9];
    const float* bf1  = (const float*)d_in[10];
    float* out = (float*)d_out;

    const int* srcI = ei;
    const int* dstI = ei + NEDGES;

    constexpr int SCAN_NBLK = (NATOMS + 1023) / 1024;   // 391

    // workspace layout — total ~227.2 MB (round-6 proven envelope).
    // rank ALIASES the start of aggB: rank's lifetime (degi -> fill) ends before the
    // first gather writes aggB. All blocks 64B-aligned.
    char* base = (char*)d_ws;
    unsigned short* hwA  = (unsigned short*)(base + 0);              // N*128 bf16 = 102,400,000
    unsigned short* aggB = (unsigned short*)(base + 102400000);      // N*128 bf16 = 102,400,000
    int*   rank      = (int*)(base + 102400000);                     // E ints (alias of aggB)
    float* dinv      = (float*)(base + 204800000);                   // N f32 = 1,600,000
    int*   row_start = (int*)(base + 206400000);                     // N+1 ints
    int2*  csr_ev    = (int2*)(base + 208000064);                    // E int2 = 12,800,000
    int*   blockSums = (int*)(base + 220800064);                     // 512 ints
    float* pool      = (float*)(base + 220802112);                   // G*128 f32 = 2,097,152
    float* ff0       = (float*)(base + 222899264);                   // G*256 f32 = 4,194,304
    short* wf0       = (short*)(base + 227093568);                   // 8*3*64*8 bf16 = 24,576 B
    short* wf1       = (short*)(base + 227118144);                   // 8*4*64*8 bf16 = 32,768 B

    // 1) degree (+rank) -> scan (+dinv) -> atomic-free CSR fill
    hipMemsetAsync(row_start, 0, (size_t)(NATOMS + 1) * sizeof(int), stream);
    k_degi<<<(NEDGES + 255) / 256, 256, 0, stream>>>(dstI, row_start, rank, NEDGES);
    k_scan1<<<SCAN_NBLK, 256, 0, stream>>>(row_start, blockSums, dinv, NATOMS);
    k_scan2<<<1, 512, 0, stream>>>(blockSums, SCAN_NBLK);
    k_scan3<<<SCAN_NBLK, 256, 0, stream>>>(row_start, blockSums, NATOMS, NEDGES);
    k_fill<<<(NEDGES + 255) / 256, 256, 0, stream>>>(srcI, dstI, row_start, rank,
                                                     csr_ev, dinv, NEDGES);

    // 2) pack weights into MFMA fragment order (bf16)
    k_packw<3, F_INN><<<8 * 3, 64, 0, stream>>>(W0, wf0);
    k_packw<4, HDIM><<<8 * 4, 64, 0, stream>>>(W1, wf1);

    // 3) layer 0: hw0 = x@W0 (bf16) ; gather -> relu(agg + b0) bf16
    //    persistent grid: 1024 blocks (4/CU resident), waves grid-stride tiles
    k_gemm_mfma<3, true, F_INN><<<1024, 256, 0, stream>>>(x, wf0, (short*)hwA, NATOMS);
    k_gather_bf<<<NATOMS / 16, 256, 0, stream>>>(hwA, aggB, row_start, csr_ev,
                                                 dinv, b0, NATOMS);

    // 4) layer 1: hw1 = h@W1 (bf16) ; gather -> relu(agg + b1) bf16
    k_gemm_mfma<4, false, HDIM><<<1024, 256, 0, stream>>>(aggB, wf1, (short*)hwA, NATOMS);
    k_gather_bf<<<NATOMS / 16, 256, 0, stream>>>(hwA, aggB, row_start, csr_ev,
                                                 dinv, b1, NATOMS);

    // 5) pool: segment max -> pool f32 [G,128]
    k_pool<<<NGRAPH, 256, 0, stream>>>(aggB, batch, pool, NATOMS);

    // 6) FF head (f32, tiny)
    k_gemm<HDIM, FF0D, true><<<NGRAPH / 64, 256, 0, stream>>>(pool, Wf0, bf0, ff0, NGRAPH);
    k_gemm<FF0D, FF1D, true><<<NGRAPH / 128, 256, 0, stream>>>(ff0, Wf1, bf1, out, NGRAPH);
}